// Round 1
// baseline (2792.570 us; speedup 1.0000x reference)
//
#include <hip/hip_runtime.h>
#include <hip/hip_bf16.h>
#include <math.h>

#define BN_ 32
#define CIN 512
#define KN 1024
#define CMID 128
#define COUT 64
#define NCLS 5
#define NUM_TOP 205
#define NUM_KEPT 409
#define NUM_DROP 410
#define ADJ_KK 204
#define EPSF 1e-8f
#define INV_DS (1.0f / 0.599609375f)

// ---------------- masks: exact stable top-k semantics via rank counting ----
__global__ __launch_bounds__(1024) void masks_kernel(const float* __restrict__ imp,
                                                     const float* __restrict__ rnd,
                                                     float* __restrict__ mTK,
                                                     float* __restrict__ mTD) {
  int b = blockIdx.x;
  int i = threadIdx.x;
  __shared__ float im[KN];
  __shared__ float rm[KN];
  __shared__ float r1[KN];
  im[i] = imp[(size_t)b * KN + i];
  rm[i] = rnd[(size_t)b * KN + i];
  __syncthreads();
  float vi = im[i];
  int rank = 0;
  for (int j = 0; j < KN; ++j) {
    float vj = im[j];
    rank += (vj > vi || (vj == vi && j < i)) ? 1 : 0;
  }
  int top = rank < NUM_TOP;
  r1[i] = top ? -10.0f : rm[i];
  __syncthreads();
  float v1 = r1[i];
  int rank1 = 0;
  for (int j = 0; j < KN; ++j) {
    float vj = r1[j];
    rank1 += (vj > v1 || (vj == v1 && j < i)) ? 1 : 0;
  }
  int kept = rank1 < NUM_KEPT;
  __syncthreads();
  r1[i] = top ? 10.0f : rm[i];
  __syncthreads();
  float v2 = r1[i];
  int rank2 = 0;
  for (int j = 0; j < KN; ++j) {
    float vj = r1[j];
    rank2 += (vj < v2 || (vj == v2 && j < i)) ? 1 : 0;
  }
  int drop = rank2 < NUM_DROP;
  mTK[(size_t)b * KN + i] = (top || kept) ? 1.0f : 0.0f;
  mTD[(size_t)b * KN + i] = (top || drop) ? 1.0f : 0.0f;
}

// ---------------- adjP row-sum reciprocals -------------------------------
__global__ void psum_kernel(const float* __restrict__ imp, float* __restrict__ invSumP) {
  int b = blockIdx.y;
  int i = blockIdx.x * 256 + threadIdx.x;
  __shared__ float im[KN];
  for (int j = threadIdx.x; j < KN; j += 256) im[j] = imp[(size_t)b * KN + j];
  __syncthreads();
  float vi = im[i];
  float s = 0.0f;
  for (int j = 0; j < KN; ++j) {
    float d = vi - im[j];
    s += expf(-d * d * 0.125f);
  }
  invSumP[(size_t)b * KN + i] = 1.0f / (s + 1.0f + EPSF);
}

// ---------------- per-column L2 norm reciprocals -------------------------
template <int C>
__global__ void colnorm_kernel(const float* __restrict__ f, float* __restrict__ inv) {
  int idx = blockIdx.x * 256 + threadIdx.x;
  int b = idx >> 10;
  int k = idx & (KN - 1);
  const float* fb = f + (size_t)b * C * KN + k;
  float ss = 0.0f;
  for (int c = 0; c < C; ++c) {
    float v = fb[(size_t)c * KN];
    ss += v * v;
  }
  inv[idx] = 1.0f / (sqrtf(ss) + EPSF);
}

// ---------------- sim GEMM: sim[i,j] = (sum_c f_ci f_cj) * inv_i * inv_j --
template <int C>
__global__ void sim_kernel(const float* __restrict__ f, const float* __restrict__ inv,
                           float* __restrict__ sim, int bstart) {
  int brel = blockIdx.z;
  int b = bstart + brel;
  int j0 = blockIdx.x * 64;
  int i0 = blockIdx.y * 64;
  const float* fb = f + (size_t)b * C * KN;
  __shared__ float As[16][65];
  __shared__ float Bs[16][65];
  float acc[4][4] = {};
  int tx = threadIdx.x & 15, ty = threadIdx.x >> 4;
  for (int c0 = 0; c0 < C; c0 += 16) {
    for (int l = threadIdx.x; l < 1024; l += 256) {
      int cc = l >> 6, v = l & 63;
      As[cc][v] = fb[(size_t)(c0 + cc) * KN + i0 + v];
      Bs[cc][v] = fb[(size_t)(c0 + cc) * KN + j0 + v];
    }
    __syncthreads();
#pragma unroll
    for (int cc = 0; cc < 16; ++cc) {
      float a[4], bb[4];
#pragma unroll
      for (int mi = 0; mi < 4; ++mi) a[mi] = As[cc][ty * 4 + mi];
#pragma unroll
      for (int nj = 0; nj < 4; ++nj) bb[nj] = Bs[cc][tx * 4 + nj];
#pragma unroll
      for (int mi = 0; mi < 4; ++mi)
#pragma unroll
        for (int nj = 0; nj < 4; ++nj) acc[mi][nj] += a[mi] * bb[nj];
    }
    __syncthreads();
  }
  float invi[4], invj[4];
#pragma unroll
  for (int mi = 0; mi < 4; ++mi) invi[mi] = inv[(size_t)b * KN + i0 + ty * 4 + mi];
#pragma unroll
  for (int nj = 0; nj < 4; ++nj) invj[nj] = inv[(size_t)b * KN + j0 + tx * 4 + nj];
#pragma unroll
  for (int mi = 0; mi < 4; ++mi) {
    float4 r = make_float4(acc[mi][0] * invi[mi] * invj[0], acc[mi][1] * invi[mi] * invj[1],
                           acc[mi][2] * invi[mi] * invj[2], acc[mi][3] * invi[mi] * invj[3]);
    *(float4*)(sim + ((size_t)brel * KN + i0 + ty * 4 + mi) * KN + j0 + tx * 4) = r;
  }
}

// ---------------- per-row 204th-largest via 4-pass radix select ----------
__global__ void thr_kernel(const float* __restrict__ sim, float* __restrict__ thrB, int bstart) {
  int i = blockIdx.x;
  int brel = blockIdx.y;
  const float* row = sim + ((size_t)brel * KN + i) * KN;
  __shared__ unsigned keys[KN];
  __shared__ int hist[256];
  __shared__ unsigned s_prefix;
  __shared__ int s_target;
  int t = threadIdx.x;
  for (int j = t; j < KN; j += 256) {
    unsigned u = __float_as_uint(row[j]);
    keys[j] = (u & 0x80000000u) ? ~u : (u | 0x80000000u);
  }
  if (t == 0) {
    s_prefix = 0u;
    s_target = ADJ_KK;
  }
  for (int shift = 24; shift >= 0; shift -= 8) {
    hist[t] = 0;
    __syncthreads();
    unsigned pf = s_prefix;
    unsigned mask_hi = (shift == 24) ? 0u : (0xFFFFFFFFu << (shift + 8));
    for (int j = t; j < KN; j += 256) {
      unsigned kk = keys[j];
      if ((kk & mask_hi) == pf) atomicAdd(&hist[(kk >> shift) & 255u], 1);
    }
    __syncthreads();
    if (t == 0) {
      int cum = 0;
      for (int bin = 255; bin >= 0; --bin) {
        cum += hist[bin];
        if (cum >= s_target) {
          s_target -= (cum - hist[bin]);
          s_prefix = pf | ((unsigned)bin << shift);
          break;
        }
      }
    }
    __syncthreads();
  }
  if (t == 0) {
    unsigned m = s_prefix;
    unsigned u = (m & 0x80000000u) ? (m & 0x7fffffffu) : ~m;
    thrB[(size_t)(bstart + brel) * KN + i] = __uint_as_float(u);
  }
}

// ------- finalize: A = norm(where(sim>=thr,sim,0)+I) + norm(adjP) in place
__global__ void finalize_kernel(float* __restrict__ A, const float* __restrict__ thrB,
                                const float* __restrict__ imp, const float* __restrict__ invSumP,
                                int bstart) {
  int i = blockIdx.x;
  int brel = blockIdx.y;
  int b = bstart + brel;
  float* row = A + ((size_t)brel * KN + i) * KN;
  int t = threadIdx.x;
  __shared__ float im[KN];
  __shared__ float red[256];
  for (int j = t; j < KN; j += 256) im[j] = imp[(size_t)b * KN + j];
  float th = thrB[(size_t)b * KN + i];
  float4 v = ((const float4*)row)[t];
  float m0 = (v.x >= th) ? v.x : 0.0f;
  float m1 = (v.y >= th) ? v.y : 0.0f;
  float m2 = (v.z >= th) ? v.z : 0.0f;
  float m3 = (v.w >= th) ? v.w : 0.0f;
  red[t] = m0 + m1 + m2 + m3;
  __syncthreads();
  for (int s = 128; s > 0; s >>= 1) {
    if (t < s) red[t] += red[t + s];
    __syncthreads();
  }
  float invF = 1.0f / (red[0] + 1.0f + EPSF);
  float vi = im[i];
  float invP = invSumP[(size_t)b * KN + i];
  int j0 = t * 4;
  float mv[4] = {m0, m1, m2, m3};
  float4 r;
  float* rp = (float*)&r;
#pragma unroll
  for (int jj = 0; jj < 4; ++jj) {
    int j = j0 + jj;
    float diag = (j == i) ? 1.0f : 0.0f;
    float d = vi - im[j];
    rp[jj] = (mv[jj] + diag) * invF + (expf(-d * d * 0.125f) + diag) * invP;
  }
  ((float4*)row)[t] = r;
}

// ---------------- per-node linear: out[b,o,k] = sum_c f[b,c,k] W[c,o] ----
template <int C, int M, bool MASK>
__global__ void linear_kernel(const float* __restrict__ f, const float* __restrict__ W,
                              float* __restrict__ outp, const float* __restrict__ mTK) {
  int o0 = blockIdx.x * 16;
  int b = blockIdx.y;
  __shared__ float Ws[C][16];
  for (int l = threadIdx.x; l < C * 16; l += 256) {
    int c = l >> 4, o = l & 15;
    Ws[c][o] = W[(size_t)c * M + o0 + o];
  }
  __syncthreads();
  int k0 = threadIdx.x * 4;
  const float* fb = f + (size_t)b * C * KN;
  float acc[16][4] = {};
  for (int c = 0; c < C; ++c) {
    float4 xv = *(const float4*)(fb + (size_t)c * KN + k0);
#pragma unroll
    for (int o = 0; o < 16; ++o) {
      float w = Ws[c][o];
      acc[o][0] += xv.x * w;
      acc[o][1] += xv.y * w;
      acc[o][2] += xv.z * w;
      acc[o][3] += xv.w * w;
    }
  }
  float ms[4] = {1.0f, 1.0f, 1.0f, 1.0f};
  if (MASK) {
#pragma unroll
    for (int jj = 0; jj < 4; ++jj) ms[jj] = mTK[(size_t)b * KN + k0 + jj] * INV_DS;
  }
#pragma unroll
  for (int o = 0; o < 16; ++o) {
    float4 r = make_float4(acc[o][0] * ms[0], acc[o][1] * ms[1], acc[o][2] * ms[2],
                           acc[o][3] * ms[3]);
    *(float4*)(outp + ((size_t)b * M + o0 + o) * KN + k0) = r;
  }
}

// ---------------- s = relu(h @ A) ----------------------------------------
template <int M>
__global__ void sgemm_kernel(const float* __restrict__ h, const float* __restrict__ A,
                             float* __restrict__ outp, int bstart) {
  int brel = blockIdx.z;
  int b = bstart + brel;
  int j0 = blockIdx.x * 64;
  int m0 = blockIdx.y * 64;
  const float* hb = h + ((size_t)b * M + m0) * KN;
  const float* Ab = A + (size_t)brel * KN * KN;
  __shared__ float Hs[16][65];
  __shared__ float As[16][65];
  float acc[4][4] = {};
  int tx = threadIdx.x & 15, ty = threadIdx.x >> 4;
  for (int k0 = 0; k0 < KN; k0 += 16) {
    for (int l = threadIdx.x; l < 1024; l += 256) {
      int mm = l >> 4, kk = l & 15;
      Hs[kk][mm] = hb[(size_t)mm * KN + k0 + kk];
    }
    for (int l = threadIdx.x; l < 1024; l += 256) {
      int kk = l >> 6, jj = l & 63;
      As[kk][jj] = Ab[(size_t)(k0 + kk) * KN + j0 + jj];
    }
    __syncthreads();
#pragma unroll
    for (int kk = 0; kk < 16; ++kk) {
      float a[4], bb[4];
#pragma unroll
      for (int mi = 0; mi < 4; ++mi) a[mi] = Hs[kk][ty * 4 + mi];
#pragma unroll
      for (int nj = 0; nj < 4; ++nj) bb[nj] = As[kk][tx * 4 + nj];
#pragma unroll
      for (int mi = 0; mi < 4; ++mi)
#pragma unroll
        for (int nj = 0; nj < 4; ++nj) acc[mi][nj] += a[mi] * bb[nj];
    }
    __syncthreads();
  }
#pragma unroll
  for (int mi = 0; mi < 4; ++mi) {
    float4 r = make_float4(fmaxf(acc[mi][0], 0.0f), fmaxf(acc[mi][1], 0.0f),
                           fmaxf(acc[mi][2], 0.0f), fmaxf(acc[mi][3], 0.0f));
    *(float4*)(outp + ((size_t)b * M + m0 + ty * 4 + mi) * KN + j0 + tx * 4) = r;
  }
}

// ---------------- reductions ---------------------------------------------
__global__ void bag12_kernel(const float* __restrict__ emb1, const float* __restrict__ mTK,
                             const float* __restrict__ mTD, const float* __restrict__ imp,
                             float* __restrict__ bagk, float* __restrict__ bagd) {
  int c = blockIdx.x, b = blockIdx.y;
  int t = threadIdx.x;
  const float* e = emb1 + ((size_t)b * CMID + c) * KN;
  const float* ir = imp + (size_t)b * KN;
  const float* m1 = mTK + (size_t)b * KN;
  const float* m2 = mTD + (size_t)b * KN;
  float s1 = 0.0f, sd = 0.0f;
  for (int k = t; k < KN; k += 256) {
    float ev = e[k] * ir[k];
    s1 += ev * m1[k];
    sd += ev * m2[k];
  }
  __shared__ float r1[256], r2[256];
  r1[t] = s1;
  r2[t] = sd;
  __syncthreads();
  for (int st = 128; st > 0; st >>= 1) {
    if (t < st) {
      r1[t] += r1[t + st];
      r2[t] += r2[t + st];
    }
    __syncthreads();
  }
  if (t == 0) {
    bagk[(size_t)b * CMID + c] = r1[0] * INV_DS;
    bagd[(size_t)b * CMID + c] = r2[0] * INV_DS;
  }
}

__global__ void bag2_kernel(const float* __restrict__ s2, const float* __restrict__ mTK,
                            const float* __restrict__ imp, float* __restrict__ bag) {
  int o = blockIdx.x, b = blockIdx.y;
  int t = threadIdx.x;
  const float* sr = s2 + ((size_t)b * COUT + o) * KN;
  const float* ir = imp + (size_t)b * KN;
  const float* mr = mTK + (size_t)b * KN;
  float s = 0.0f;
  for (int k = t; k < KN; k += 256) s += sr[k] * mr[k] * ir[k];
  __shared__ float red[256];
  red[t] = s;
  __syncthreads();
  for (int st = 128; st > 0; st >>= 1) {
    if (t < st) red[t] += red[t + st];
    __syncthreads();
  }
  if (t == 0) bag[(size_t)b * COUT + o] = red[0];
}

__global__ void pooled_kernel(const float* __restrict__ x, const float* __restrict__ imp,
                              float* __restrict__ pooled) {
  int c = blockIdx.x, b = blockIdx.y;
  int t = threadIdx.x;
  const float* xr = x + ((size_t)b * CIN + c) * KN;
  const float* ir = imp + (size_t)b * KN;
  float s = 0.0f;
  for (int k = t; k < KN; k += 256) s += xr[k] * ir[k];
  __shared__ float red[256];
  red[t] = s;
  __syncthreads();
  for (int st = 128; st > 0; st >>= 1) {
    if (t < st) red[t] += red[t + st];
    __syncthreads();
  }
  if (t == 0) pooled[(size_t)b * CIN + c] = red[0];
}

__global__ void final_kernel(const float* __restrict__ pooled, const float* __restrict__ bag,
                             const float* __restrict__ id_w, const float* __restrict__ id_b,
                             const float* __restrict__ fc_w, float* __restrict__ out) {
  int b = blockIdx.x;
  int o = threadIdx.x;
  __shared__ float v[COUT];
  float s = id_b[o];
  const float* pr = pooled + (size_t)b * CIN;
  for (int c = 0; c < CIN; ++c) s += pr[c] * id_w[(size_t)c * COUT + o];
  v[o] = bag[(size_t)b * COUT + o] + fmaxf(s, 0.0f);
  __syncthreads();
  if (o < NCLS) {
    float acc = 0.0f;
    for (int oo = 0; oo < COUT; ++oo) acc += v[oo] * fc_w[(size_t)oo * NCLS + o];
    out[(size_t)b * NCLS + o] = acc;
  }
}

// ---------------- launch --------------------------------------------------
extern "C" void kernel_launch(void* const* d_in, const int* in_sizes, int n_in,
                              void* d_out, int out_size, void* d_ws, size_t ws_size,
                              hipStream_t stream) {
  const float* x = (const float*)d_in[0];
  const float* imp = (const float*)d_in[1];
  const float* rnd = (const float*)d_in[2];
  const float* W1 = (const float*)d_in[3];
  const float* W2 = (const float*)d_in[4];
  const float* fc_w = (const float*)d_in[5];
  const float* id_w = (const float*)d_in[6];
  const float* id_b = (const float*)d_in[7];
  float* out = (float*)d_out;
  float* emb1 = out + BN_ * NCLS;
  float* bagk = emb1 + (size_t)BN_ * CMID * KN;
  float* bagd = bagk + (size_t)BN_ * CMID;

  float* w = (float*)d_ws;
  size_t off = 0;
  auto take = [&](size_t n) {
    float* p = w + off;
    off += n;
    return p;
  };
  float* invSumP = take((size_t)BN_ * KN);
  float* invNX = take((size_t)BN_ * KN);
  float* invNE = take((size_t)BN_ * KN);
  float* thrB = take((size_t)BN_ * KN);
  float* mTK = take((size_t)BN_ * KN);
  float* mTD = take((size_t)BN_ * KN);
  float* h = take((size_t)BN_ * CMID * KN);
  float* h2 = take((size_t)BN_ * COUT * KN);
  float* s2 = take((size_t)BN_ * COUT * KN);
  float* bag = take((size_t)BN_ * COUT);
  float* pooled = take((size_t)BN_ * CIN);
  long long avail = (long long)(ws_size / 4) - (long long)off;
  int nb = 1;
  const int cands[6] = {32, 16, 8, 4, 2, 1};
  for (int ci = 0; ci < 6; ++ci) {
    if ((long long)cands[ci] * KN * KN <= avail) {
      nb = cands[ci];
      break;
    }
  }
  float* simA = w + off;

  masks_kernel<<<BN_, 1024, 0, stream>>>(imp, rnd, mTK, mTD);
  psum_kernel<<<dim3(KN / 256, BN_), 256, 0, stream>>>(imp, invSumP);
  colnorm_kernel<CIN><<<(BN_ * KN) / 256, 256, 0, stream>>>(x, invNX);
  linear_kernel<CIN, CMID, false><<<dim3(CMID / 16, BN_), 256, 0, stream>>>(x, W1, h, nullptr);

  for (int bs = 0; bs < BN_; bs += nb) {
    sim_kernel<CIN><<<dim3(16, 16, nb), 256, 0, stream>>>(x, invNX, simA, bs);
    thr_kernel<<<dim3(KN, nb), 256, 0, stream>>>(simA, thrB, bs);
    finalize_kernel<<<dim3(KN, nb), 256, 0, stream>>>(simA, thrB, imp, invSumP, bs);
    sgemm_kernel<CMID><<<dim3(16, CMID / 64, nb), 256, 0, stream>>>(h, simA, emb1, bs);
  }

  colnorm_kernel<CMID><<<(BN_ * KN) / 256, 256, 0, stream>>>(emb1, invNE);
  linear_kernel<CMID, COUT, true><<<dim3(COUT / 16, BN_), 256, 0, stream>>>(emb1, W2, h2, mTK);

  for (int bs = 0; bs < BN_; bs += nb) {
    sim_kernel<CMID><<<dim3(16, 16, nb), 256, 0, stream>>>(emb1, invNE, simA, bs);
    thr_kernel<<<dim3(KN, nb), 256, 0, stream>>>(simA, thrB, bs);
    finalize_kernel<<<dim3(KN, nb), 256, 0, stream>>>(simA, thrB, imp, invSumP, bs);
    sgemm_kernel<COUT><<<dim3(16, COUT / 64, nb), 256, 0, stream>>>(h2, simA, s2, bs);
  }

  bag12_kernel<<<dim3(CMID, BN_), 256, 0, stream>>>(emb1, mTK, mTD, imp, bagk, bagd);
  bag2_kernel<<<dim3(COUT, BN_), 256, 0, stream>>>(s2, mTK, imp, bag);
  pooled_kernel<<<dim3(CIN, BN_), 256, 0, stream>>>(x, imp, pooled);
  final_kernel<<<BN_, 64, 0, stream>>>(pooled, bag, id_w, id_b, fc_w, out);
}

// Round 2
// 2156.795 us; speedup vs baseline: 1.2948x; 1.2948x over previous
//
#include <hip/hip_runtime.h>
#include <hip/hip_bf16.h>
#include <math.h>

#define BN_ 32
#define CIN 512
#define KN 1024
#define CMID 128
#define COUT 64
#define NCLS 5
#define NUM_TOP 205
#define NUM_KEPT 409
#define NUM_DROP 410
#define ADJ_KK 204
#define EPSF 1e-8f
#define INV_DS (1.0f / 0.599609375f)

typedef __bf16 bf16x8 __attribute__((ext_vector_type(8)));
typedef float f32x4 __attribute__((ext_vector_type(4)));

// ---------------- masks: exact stable top-k semantics via rank counting ----
__global__ __launch_bounds__(1024) void masks_kernel(const float* __restrict__ imp,
                                                     const float* __restrict__ rnd,
                                                     float* __restrict__ mTK,
                                                     float* __restrict__ mTD) {
  int b = blockIdx.x;
  int i = threadIdx.x;
  __shared__ float im[KN];
  __shared__ float rm[KN];
  __shared__ float r1[KN];
  im[i] = imp[(size_t)b * KN + i];
  rm[i] = rnd[(size_t)b * KN + i];
  __syncthreads();
  float vi = im[i];
  int rank = 0;
  for (int j = 0; j < KN; ++j) {
    float vj = im[j];
    rank += (vj > vi || (vj == vi && j < i)) ? 1 : 0;
  }
  int top = rank < NUM_TOP;
  r1[i] = top ? -10.0f : rm[i];
  __syncthreads();
  float v1 = r1[i];
  int rank1 = 0;
  for (int j = 0; j < KN; ++j) {
    float vj = r1[j];
    rank1 += (vj > v1 || (vj == v1 && j < i)) ? 1 : 0;
  }
  int kept = rank1 < NUM_KEPT;
  __syncthreads();
  r1[i] = top ? 10.0f : rm[i];
  __syncthreads();
  float v2 = r1[i];
  int rank2 = 0;
  for (int j = 0; j < KN; ++j) {
    float vj = r1[j];
    rank2 += (vj < v2 || (vj == v2 && j < i)) ? 1 : 0;
  }
  int drop = rank2 < NUM_DROP;
  mTK[(size_t)b * KN + i] = (top || kept) ? 1.0f : 0.0f;
  mTD[(size_t)b * KN + i] = (top || drop) ? 1.0f : 0.0f;
}

// ---------------- adjP row-sum reciprocals -------------------------------
__global__ void psum_kernel(const float* __restrict__ imp, float* __restrict__ invSumP) {
  int b = blockIdx.y;
  int i = blockIdx.x * 256 + threadIdx.x;
  __shared__ float im[KN];
  for (int j = threadIdx.x; j < KN; j += 256) im[j] = imp[(size_t)b * KN + j];
  __syncthreads();
  float vi = im[i];
  float s = 0.0f;
  for (int j = 0; j < KN; ++j) {
    float d = vi - im[j];
    s += expf(-d * d * 0.125f);
  }
  invSumP[(size_t)b * KN + i] = 1.0f / (s + 1.0f + EPSF);
}

// ---------------- per-column L2 norm reciprocals -------------------------
template <int C>
__global__ void colnorm_kernel(const float* __restrict__ f, float* __restrict__ inv) {
  int idx = blockIdx.x * 256 + threadIdx.x;
  int b = idx >> 10;
  int k = idx & (KN - 1);
  const float* fb = f + (size_t)b * C * KN + k;
  float ss = 0.0f;
  for (int c = 0; c < C; ++c) {
    float v = fb[(size_t)c * KN];
    ss += v * v;
  }
  inv[idx] = 1.0f / (sqrtf(ss) + EPSF);
}

// ------- transpose + normalize + bf16: oT[b][k][c] = f[b][c][k]*inv[b][k] --
template <int C>
__global__ void xpose_kernel(const float* __restrict__ f, const float* __restrict__ inv,
                             __hip_bfloat16* __restrict__ oT) {
  int b = blockIdx.z;
  int k0 = blockIdx.x * 64;
  int c0 = blockIdx.y * 64;
  __shared__ float t[64][65];
  const float* fb = f + (size_t)b * C * KN;
  int tx = threadIdx.x & 63;
  int ty = threadIdx.x >> 6;
  for (int r = 0; r < 64; r += 4) t[r + ty][tx] = fb[(size_t)(c0 + r + ty) * KN + k0 + tx];
  __syncthreads();
  __hip_bfloat16* ob = oT + (size_t)b * KN * C;
  for (int r = 0; r < 64; r += 4) {
    int k = r + ty;
    float s = inv[(size_t)b * KN + k0 + k];
    ob[(size_t)(k0 + k) * C + c0 + tx] = __float2bfloat16(t[tx][k] * s);
  }
}

// ---------------- MFMA sim: sim = XnT * XnT^T (Gram, symmetric) ----------
template <int C>
__global__ __launch_bounds__(256) void simf_kernel(const __hip_bfloat16* __restrict__ xT,
                                                   float* __restrict__ sim, int bstart) {
  int brel = blockIdx.z;
  int b = bstart + brel;
  int lane = threadIdx.x & 63;
  int wid = threadIdx.x >> 6;
  int i0 = blockIdx.y * 128 + (wid >> 1) * 64;
  int j0 = blockIdx.x * 128 + (wid & 1) * 64;
  const __hip_bfloat16* X = xT + (size_t)b * KN * C;
  int lrow = lane & 15;
  int koff = (lane >> 4) * 8;
  f32x4 acc[4][4] = {};
#pragma unroll 4
  for (int c0 = 0; c0 < C; c0 += 32) {
    bf16x8 a[4], bb[4];
#pragma unroll
    for (int m = 0; m < 4; ++m)
      a[m] = *reinterpret_cast<const bf16x8*>(X + (size_t)(i0 + m * 16 + lrow) * C + c0 + koff);
#pragma unroll
    for (int n = 0; n < 4; ++n)
      bb[n] = *reinterpret_cast<const bf16x8*>(X + (size_t)(j0 + n * 16 + lrow) * C + c0 + koff);
#pragma unroll
    for (int m = 0; m < 4; ++m)
#pragma unroll
      for (int n = 0; n < 4; ++n)
        acc[m][n] = __builtin_amdgcn_mfma_f32_16x16x32_bf16(a[m], bb[n], acc[m][n], 0, 0, 0);
  }
  int orow = (lane >> 4) * 4;
  int ocol = lane & 15;
  float* simb = sim + (size_t)brel * KN * KN;
#pragma unroll
  for (int m = 0; m < 4; ++m)
#pragma unroll
    for (int n = 0; n < 4; ++n) {
#pragma unroll
      for (int r = 0; r < 4; ++r)
        simb[(size_t)(i0 + m * 16 + orow + r) * KN + j0 + n * 16 + ocol] = acc[m][n][r];
    }
}

// ---------------- per-row 204th-largest via 4-pass radix select ----------
__global__ void thr_kernel(const float* __restrict__ sim, float* __restrict__ thrB, int bstart) {
  int i = blockIdx.x;
  int brel = blockIdx.y;
  const float* row = sim + ((size_t)brel * KN + i) * KN;
  __shared__ unsigned keys[KN];
  __shared__ int hist[256];
  __shared__ unsigned s_prefix;
  __shared__ int s_target;
  int t = threadIdx.x;
  for (int j = t; j < KN; j += 256) {
    unsigned u = __float_as_uint(row[j]);
    keys[j] = (u & 0x80000000u) ? ~u : (u | 0x80000000u);
  }
  if (t == 0) {
    s_prefix = 0u;
    s_target = ADJ_KK;
  }
  for (int shift = 24; shift >= 0; shift -= 8) {
    hist[t] = 0;
    __syncthreads();
    unsigned pf = s_prefix;
    unsigned mask_hi = (shift == 24) ? 0u : (0xFFFFFFFFu << (shift + 8));
    for (int j = t; j < KN; j += 256) {
      unsigned kk = keys[j];
      if ((kk & mask_hi) == pf) atomicAdd(&hist[(kk >> shift) & 255u], 1);
    }
    __syncthreads();
    if (t == 0) {
      int cum = 0;
      for (int bin = 255; bin >= 0; --bin) {
        cum += hist[bin];
        if (cum >= s_target) {
          s_target -= (cum - hist[bin]);
          s_prefix = pf | ((unsigned)bin << shift);
          break;
        }
      }
    }
    __syncthreads();
  }
  if (t == 0) {
    unsigned m = s_prefix;
    unsigned u = (m & 0x80000000u) ? (m & 0x7fffffffu) : ~m;
    thrB[(size_t)(bstart + brel) * KN + i] = __uint_as_float(u);
  }
}

// ------- finalize: A = norm(where(sim>=thr,sim,0)+I) + norm(adjP) in place
__global__ void finalize_kernel(float* __restrict__ A, const float* __restrict__ thrB,
                                const float* __restrict__ imp, const float* __restrict__ invSumP,
                                int bstart) {
  int i = blockIdx.x;
  int brel = blockIdx.y;
  int b = bstart + brel;
  float* row = A + ((size_t)brel * KN + i) * KN;
  int t = threadIdx.x;
  __shared__ float im[KN];
  __shared__ float red[256];
  for (int j = t; j < KN; j += 256) im[j] = imp[(size_t)b * KN + j];
  float th = thrB[(size_t)b * KN + i];
  float4 v = ((const float4*)row)[t];
  float m0 = (v.x >= th) ? v.x : 0.0f;
  float m1 = (v.y >= th) ? v.y : 0.0f;
  float m2 = (v.z >= th) ? v.z : 0.0f;
  float m3 = (v.w >= th) ? v.w : 0.0f;
  red[t] = m0 + m1 + m2 + m3;
  __syncthreads();
  for (int s = 128; s > 0; s >>= 1) {
    if (t < s) red[t] += red[t + s];
    __syncthreads();
  }
  float invF = 1.0f / (red[0] + 1.0f + EPSF);
  float vi = im[i];
  float invP = invSumP[(size_t)b * KN + i];
  int j0 = t * 4;
  float mv[4] = {m0, m1, m2, m3};
  float4 r;
  float* rp = (float*)&r;
#pragma unroll
  for (int jj = 0; jj < 4; ++jj) {
    int j = j0 + jj;
    float diag = (j == i) ? 1.0f : 0.0f;
    float d = vi - im[j];
    rp[jj] = (mv[jj] + diag) * invF + (expf(-d * d * 0.125f) + diag) * invP;
  }
  ((float4*)row)[t] = r;
}

// ---------------- per-node linear: out[b,o,k] = sum_c f[b,c,k] W[c,o] ----
template <int C, int M, bool MASK>
__global__ void linear_kernel(const float* __restrict__ f, const float* __restrict__ W,
                              float* __restrict__ outp, const float* __restrict__ mTK) {
  int o0 = blockIdx.x * 16;
  int b = blockIdx.y;
  __shared__ float Ws[C][16];
  for (int l = threadIdx.x; l < C * 16; l += 256) {
    int c = l >> 4, o = l & 15;
    Ws[c][o] = W[(size_t)c * M + o0 + o];
  }
  __syncthreads();
  int k0 = threadIdx.x * 4;
  const float* fb = f + (size_t)b * C * KN;
  float acc[16][4] = {};
  for (int c = 0; c < C; ++c) {
    float4 xv = *(const float4*)(fb + (size_t)c * KN + k0);
#pragma unroll
    for (int o = 0; o < 16; ++o) {
      float w = Ws[c][o];
      acc[o][0] += xv.x * w;
      acc[o][1] += xv.y * w;
      acc[o][2] += xv.z * w;
      acc[o][3] += xv.w * w;
    }
  }
  float ms[4] = {1.0f, 1.0f, 1.0f, 1.0f};
  if (MASK) {
#pragma unroll
    for (int jj = 0; jj < 4; ++jj) ms[jj] = mTK[(size_t)b * KN + k0 + jj] * INV_DS;
  }
#pragma unroll
  for (int o = 0; o < 16; ++o) {
    float4 r = make_float4(acc[o][0] * ms[0], acc[o][1] * ms[1], acc[o][2] * ms[2],
                           acc[o][3] * ms[3]);
    *(float4*)(outp + ((size_t)b * M + o0 + o) * KN + k0) = r;
  }
}

// ---------------- s = relu(h @ A) ----------------------------------------
template <int M>
__global__ void sgemm_kernel(const float* __restrict__ h, const float* __restrict__ A,
                             float* __restrict__ outp, int bstart) {
  int brel = blockIdx.z;
  int b = bstart + brel;
  int j0 = blockIdx.x * 64;
  int m0 = blockIdx.y * 64;
  const float* hb = h + ((size_t)b * M + m0) * KN;
  const float* Ab = A + (size_t)brel * KN * KN;
  __shared__ float Hs[16][65];
  __shared__ float As[16][65];
  float acc[4][4] = {};
  int tx = threadIdx.x & 15, ty = threadIdx.x >> 4;
  for (int k0 = 0; k0 < KN; k0 += 16) {
    for (int l = threadIdx.x; l < 1024; l += 256) {
      int mm = l >> 4, kk = l & 15;
      Hs[kk][mm] = hb[(size_t)mm * KN + k0 + kk];
    }
    for (int l = threadIdx.x; l < 1024; l += 256) {
      int kk = l >> 6, jj = l & 63;
      As[kk][jj] = Ab[(size_t)(k0 + kk) * KN + j0 + jj];
    }
    __syncthreads();
#pragma unroll
    for (int kk = 0; kk < 16; ++kk) {
      float a[4], bb[4];
#pragma unroll
      for (int mi = 0; mi < 4; ++mi) a[mi] = Hs[kk][ty * 4 + mi];
#pragma unroll
      for (int nj = 0; nj < 4; ++nj) bb[nj] = As[kk][tx * 4 + nj];
#pragma unroll
      for (int mi = 0; mi < 4; ++mi)
#pragma unroll
        for (int nj = 0; nj < 4; ++nj) acc[mi][nj] += a[mi] * bb[nj];
    }
    __syncthreads();
  }
#pragma unroll
  for (int mi = 0; mi < 4; ++mi) {
    float4 r = make_float4(fmaxf(acc[mi][0], 0.0f), fmaxf(acc[mi][1], 0.0f),
                           fmaxf(acc[mi][2], 0.0f), fmaxf(acc[mi][3], 0.0f));
    *(float4*)(outp + ((size_t)b * M + m0 + ty * 4 + mi) * KN + j0 + tx * 4) = r;
  }
}

// ---------------- reductions ---------------------------------------------
__global__ void bag12_kernel(const float* __restrict__ emb1, const float* __restrict__ mTK,
                             const float* __restrict__ mTD, const float* __restrict__ imp,
                             float* __restrict__ bagk, float* __restrict__ bagd) {
  int c = blockIdx.x, b = blockIdx.y;
  int t = threadIdx.x;
  const float* e = emb1 + ((size_t)b * CMID + c) * KN;
  const float* ir = imp + (size_t)b * KN;
  const float* m1 = mTK + (size_t)b * KN;
  const float* m2 = mTD + (size_t)b * KN;
  float s1 = 0.0f, sd = 0.0f;
  for (int k = t; k < KN; k += 256) {
    float ev = e[k] * ir[k];
    s1 += ev * m1[k];
    sd += ev * m2[k];
  }
  __shared__ float r1[256], r2[256];
  r1[t] = s1;
  r2[t] = sd;
  __syncthreads();
  for (int st = 128; st > 0; st >>= 1) {
    if (t < st) {
      r1[t] += r1[t + st];
      r2[t] += r2[t + st];
    }
    __syncthreads();
  }
  if (t == 0) {
    bagk[(size_t)b * CMID + c] = r1[0] * INV_DS;
    bagd[(size_t)b * CMID + c] = r2[0] * INV_DS;
  }
}

__global__ void bag2_kernel(const float* __restrict__ s2, const float* __restrict__ mTK,
                            const float* __restrict__ imp, float* __restrict__ bag) {
  int o = blockIdx.x, b = blockIdx.y;
  int t = threadIdx.x;
  const float* sr = s2 + ((size_t)b * COUT + o) * KN;
  const float* ir = imp + (size_t)b * KN;
  const float* mr = mTK + (size_t)b * KN;
  float s = 0.0f;
  for (int k = t; k < KN; k += 256) s += sr[k] * mr[k] * ir[k];
  __shared__ float red[256];
  red[t] = s;
  __syncthreads();
  for (int st = 128; st > 0; st >>= 1) {
    if (t < st) red[t] += red[t + st];
    __syncthreads();
  }
  if (t == 0) bag[(size_t)b * COUT + o] = red[0];
}

__global__ void pooled_kernel(const float* __restrict__ x, const float* __restrict__ imp,
                              float* __restrict__ pooled) {
  int c = blockIdx.x, b = blockIdx.y;
  int t = threadIdx.x;
  const float* xr = x + ((size_t)b * CIN + c) * KN;
  const float* ir = imp + (size_t)b * KN;
  float s = 0.0f;
  for (int k = t; k < KN; k += 256) s += xr[k] * ir[k];
  __shared__ float red[256];
  red[t] = s;
  __syncthreads();
  for (int st = 128; st > 0; st >>= 1) {
    if (t < st) red[t] += red[t + st];
    __syncthreads();
  }
  if (t == 0) pooled[(size_t)b * CIN + c] = red[0];
}

__global__ void final_kernel(const float* __restrict__ pooled, const float* __restrict__ bag,
                             const float* __restrict__ id_w, const float* __restrict__ id_b,
                             const float* __restrict__ fc_w, float* __restrict__ out) {
  int b = blockIdx.x;
  int o = threadIdx.x;
  __shared__ float v[COUT];
  float s = id_b[o];
  const float* pr = pooled + (size_t)b * CIN;
  for (int c = 0; c < CIN; ++c) s += pr[c] * id_w[(size_t)c * COUT + o];
  v[o] = bag[(size_t)b * COUT + o] + fmaxf(s, 0.0f);
  __syncthreads();
  if (o < NCLS) {
    float acc = 0.0f;
    for (int oo = 0; oo < COUT; ++oo) acc += v[oo] * fc_w[(size_t)oo * NCLS + o];
    out[(size_t)b * NCLS + o] = acc;
  }
}

// ---------------- launch --------------------------------------------------
extern "C" void kernel_launch(void* const* d_in, const int* in_sizes, int n_in,
                              void* d_out, int out_size, void* d_ws, size_t ws_size,
                              hipStream_t stream) {
  const float* x = (const float*)d_in[0];
  const float* imp = (const float*)d_in[1];
  const float* rnd = (const float*)d_in[2];
  const float* W1 = (const float*)d_in[3];
  const float* W2 = (const float*)d_in[4];
  const float* fc_w = (const float*)d_in[5];
  const float* id_w = (const float*)d_in[6];
  const float* id_b = (const float*)d_in[7];
  float* out = (float*)d_out;
  float* emb1 = out + BN_ * NCLS;
  float* bagk = emb1 + (size_t)BN_ * CMID * KN;
  float* bagd = bagk + (size_t)BN_ * CMID;

  float* w = (float*)d_ws;
  size_t off = 0;
  auto take = [&](size_t n) {
    float* p = w + off;
    off += n;
    return p;
  };
  float* invSumP = take((size_t)BN_ * KN);
  float* invNX = take((size_t)BN_ * KN);
  float* invNE = take((size_t)BN_ * KN);
  float* thrB = take((size_t)BN_ * KN);
  float* mTK = take((size_t)BN_ * KN);
  float* mTD = take((size_t)BN_ * KN);
  float* h = take((size_t)BN_ * CMID * KN);
  float* h2 = take((size_t)BN_ * COUT * KN);
  float* s2 = take((size_t)BN_ * COUT * KN);
  float* bag = take((size_t)BN_ * COUT);
  float* pooled = take((size_t)BN_ * CIN);
  __hip_bfloat16* xnT = (__hip_bfloat16*)take((size_t)BN_ * CIN * KN / 2);
  __hip_bfloat16* enT = (__hip_bfloat16*)take((size_t)BN_ * CMID * KN / 2);
  long long avail = (long long)(ws_size / 4) - (long long)off;
  int nb = 1;
  const int cands[6] = {32, 16, 8, 4, 2, 1};
  for (int ci = 0; ci < 6; ++ci) {
    if ((long long)cands[ci] * KN * KN <= avail) {
      nb = cands[ci];
      break;
    }
  }
  float* simA = w + off;

  masks_kernel<<<BN_, 1024, 0, stream>>>(imp, rnd, mTK, mTD);
  psum_kernel<<<dim3(KN / 256, BN_), 256, 0, stream>>>(imp, invSumP);
  colnorm_kernel<CIN><<<(BN_ * KN) / 256, 256, 0, stream>>>(x, invNX);
  xpose_kernel<CIN><<<dim3(KN / 64, CIN / 64, BN_), 256, 0, stream>>>(x, invNX, xnT);
  linear_kernel<CIN, CMID, false><<<dim3(CMID / 16, BN_), 256, 0, stream>>>(x, W1, h, nullptr);

  for (int bs = 0; bs < BN_; bs += nb) {
    simf_kernel<CIN><<<dim3(KN / 128, KN / 128, nb), 256, 0, stream>>>(xnT, simA, bs);
    thr_kernel<<<dim3(KN, nb), 256, 0, stream>>>(simA, thrB, bs);
    finalize_kernel<<<dim3(KN, nb), 256, 0, stream>>>(simA, thrB, imp, invSumP, bs);
    sgemm_kernel<CMID><<<dim3(16, CMID / 64, nb), 256, 0, stream>>>(h, simA, emb1, bs);
  }

  colnorm_kernel<CMID><<<(BN_ * KN) / 256, 256, 0, stream>>>(emb1, invNE);
  xpose_kernel<CMID><<<dim3(KN / 64, CMID / 64, BN_), 256, 0, stream>>>(emb1, invNE, enT);
  linear_kernel<CMID, COUT, true><<<dim3(COUT / 16, BN_), 256, 0, stream>>>(emb1, W2, h2, mTK);

  for (int bs = 0; bs < BN_; bs += nb) {
    simf_kernel<CMID><<<dim3(KN / 128, KN / 128, nb), 256, 0, stream>>>(enT, simA, bs);
    thr_kernel<<<dim3(KN, nb), 256, 0, stream>>>(simA, thrB, bs);
    finalize_kernel<<<dim3(KN, nb), 256, 0, stream>>>(simA, thrB, imp, invSumP, bs);
    sgemm_kernel<COUT><<<dim3(16, COUT / 64, nb), 256, 0, stream>>>(h2, simA, s2, bs);
  }

  bag12_kernel<<<dim3(CMID, BN_), 256, 0, stream>>>(emb1, mTK, mTD, imp, bagk, bagd);
  bag2_kernel<<<dim3(COUT, BN_), 256, 0, stream>>>(s2, mTK, imp, bag);
  pooled_kernel<<<dim3(CIN, BN_), 256, 0, stream>>>(x, imp, pooled);
  final_kernel<<<BN_, 64, 0, stream>>>(pooled, bag, id_w, id_b, fc_w, out);
}

// Round 3
// 1171.893 us; speedup vs baseline: 2.3830x; 1.8404x over previous
//
#include <hip/hip_runtime.h>
#include <hip/hip_bf16.h>
#include <math.h>

#define BN_ 32
#define CIN 512
#define KN 1024
#define CMID 128
#define COUT 64
#define NCLS 5
#define NUM_TOP 205
#define NUM_KEPT 409
#define NUM_DROP 410
#define ADJ_KK 204
#define EPSF 1e-8f
#define INV_DS (1.0f / 0.599609375f)

typedef __bf16 bf16x8 __attribute__((ext_vector_type(8)));
typedef float f32x4 __attribute__((ext_vector_type(4)));

// ---------------- masks: exact stable top-k semantics via rank counting ----
__global__ __launch_bounds__(1024) void masks_kernel(const float* __restrict__ imp,
                                                     const float* __restrict__ rnd,
                                                     float* __restrict__ mTK,
                                                     float* __restrict__ mTD) {
  int b = blockIdx.x;
  int i = threadIdx.x;
  __shared__ float im[KN];
  __shared__ float rm[KN];
  __shared__ float r1[KN];
  im[i] = imp[(size_t)b * KN + i];
  rm[i] = rnd[(size_t)b * KN + i];
  __syncthreads();
  float vi = im[i];
  int rank = 0;
  for (int j = 0; j < KN; ++j) {
    float vj = im[j];
    rank += (vj > vi || (vj == vi && j < i)) ? 1 : 0;
  }
  int top = rank < NUM_TOP;
  r1[i] = top ? -10.0f : rm[i];
  __syncthreads();
  float v1 = r1[i];
  int rank1 = 0;
  for (int j = 0; j < KN; ++j) {
    float vj = r1[j];
    rank1 += (vj > v1 || (vj == v1 && j < i)) ? 1 : 0;
  }
  int kept = rank1 < NUM_KEPT;
  __syncthreads();
  r1[i] = top ? 10.0f : rm[i];
  __syncthreads();
  float v2 = r1[i];
  int rank2 = 0;
  for (int j = 0; j < KN; ++j) {
    float vj = r1[j];
    rank2 += (vj < v2 || (vj == v2 && j < i)) ? 1 : 0;
  }
  int drop = rank2 < NUM_DROP;
  mTK[(size_t)b * KN + i] = (top || kept) ? 1.0f : 0.0f;
  mTD[(size_t)b * KN + i] = (top || drop) ? 1.0f : 0.0f;
}

// ---------------- adjP row-sum reciprocals -------------------------------
__global__ void psum_kernel(const float* __restrict__ imp, float* __restrict__ invSumP) {
  int b = blockIdx.y;
  int i = blockIdx.x * 256 + threadIdx.x;
  __shared__ float im[KN];
  for (int j = threadIdx.x; j < KN; j += 256) im[j] = imp[(size_t)b * KN + j];
  __syncthreads();
  float vi = im[i];
  float s = 0.0f;
  for (int j = 0; j < KN; ++j) {
    float d = vi - im[j];
    s += __expf(-d * d * 0.125f);
  }
  invSumP[(size_t)b * KN + i] = 1.0f / (s + 1.0f + EPSF);
}

// ---------------- per-column L2 norm reciprocals -------------------------
template <int C>
__global__ void colnorm_kernel(const float* __restrict__ f, float* __restrict__ inv) {
  int idx = blockIdx.x * 256 + threadIdx.x;
  int b = idx >> 10;
  int k = idx & (KN - 1);
  const float* fb = f + (size_t)b * C * KN + k;
  float ss = 0.0f;
  for (int c = 0; c < C; ++c) {
    float v = fb[(size_t)c * KN];
    ss += v * v;
  }
  inv[idx] = 1.0f / (sqrtf(ss) + EPSF);
}

// ------- transpose + normalize + bf16: oT[b][k][c] = f[b][c][k]*inv[b][k] --
template <int C>
__global__ void xpose_kernel(const float* __restrict__ f, const float* __restrict__ inv,
                             __hip_bfloat16* __restrict__ oT) {
  int b = blockIdx.z;
  int k0 = blockIdx.x * 64;
  int c0 = blockIdx.y * 64;
  __shared__ float t[64][65];
  const float* fb = f + (size_t)b * C * KN;
  int tx = threadIdx.x & 63;
  int ty = threadIdx.x >> 6;
  for (int r = 0; r < 64; r += 4) t[r + ty][tx] = fb[(size_t)(c0 + r + ty) * KN + k0 + tx];
  __syncthreads();
  __hip_bfloat16* ob = oT + (size_t)b * KN * C;
  for (int r = 0; r < 64; r += 4) {
    int k = r + ty;
    float s = inv[(size_t)b * KN + k0 + k];
    ob[(size_t)(k0 + k) * C + c0 + tx] = __float2bfloat16(t[tx][k] * s);
  }
}

// ---------------- MFMA sim: sim = XnT * XnT^T (Gram, symmetric) ----------
template <int C>
__global__ __launch_bounds__(256) void simf_kernel(const __hip_bfloat16* __restrict__ xT,
                                                   float* __restrict__ sim, int bstart) {
  int brel = blockIdx.z;
  int b = bstart + brel;
  int lane = threadIdx.x & 63;
  int wid = threadIdx.x >> 6;
  int i0 = blockIdx.y * 128 + (wid >> 1) * 64;
  int j0 = blockIdx.x * 128 + (wid & 1) * 64;
  const __hip_bfloat16* X = xT + (size_t)b * KN * C;
  int lrow = lane & 15;
  int koff = (lane >> 4) * 8;
  f32x4 acc[4][4] = {};
#pragma unroll 4
  for (int c0 = 0; c0 < C; c0 += 32) {
    bf16x8 a[4], bb[4];
#pragma unroll
    for (int m = 0; m < 4; ++m)
      a[m] = *reinterpret_cast<const bf16x8*>(X + (size_t)(i0 + m * 16 + lrow) * C + c0 + koff);
#pragma unroll
    for (int n = 0; n < 4; ++n)
      bb[n] = *reinterpret_cast<const bf16x8*>(X + (size_t)(j0 + n * 16 + lrow) * C + c0 + koff);
#pragma unroll
    for (int m = 0; m < 4; ++m)
#pragma unroll
      for (int n = 0; n < 4; ++n)
        acc[m][n] = __builtin_amdgcn_mfma_f32_16x16x32_bf16(a[m], bb[n], acc[m][n], 0, 0, 0);
  }
  int orow = (lane >> 4) * 4;
  int ocol = lane & 15;
  float* simb = sim + (size_t)brel * KN * KN;
#pragma unroll
  for (int m = 0; m < 4; ++m)
#pragma unroll
    for (int n = 0; n < 4; ++n) {
#pragma unroll
      for (int r = 0; r < 4; ++r)
        simb[(size_t)(i0 + m * 16 + orow + r) * KN + j0 + n * 16 + ocol] = acc[m][n][r];
    }
}

// ------- fused per-wave threshold select + finalize ----------------------
// One row per wave; 4 rows per block. Exact 204th-largest via 32-step
// bit-building bisection on monotone u32 keys held in registers, then
// A = norm(where(sim>=thr,sim,0)+I) + norm(adjP) written in place.
__global__ __launch_bounds__(256) void thrfin_kernel(float* __restrict__ A,
                                                     const float* __restrict__ imp,
                                                     const float* __restrict__ invSumP,
                                                     int bstart) {
  int brel = blockIdx.y;
  int b = bstart + brel;
  int wid = threadIdx.x >> 6;
  int lane = threadIdx.x & 63;
  int i = blockIdx.x * 4 + wid;
  float* row = A + ((size_t)brel * KN + i) * KN;
  __shared__ float im[KN];
  ((float4*)im)[threadIdx.x] = ((const float4*)(imp + (size_t)b * KN))[threadIdx.x];
  __syncthreads();

  float4 v[4];
  unsigned key[16];
#pragma unroll
  for (int q = 0; q < 4; ++q) v[q] = ((const float4*)row)[lane + 64 * q];
#pragma unroll
  for (int q = 0; q < 4; ++q) {
    const float* pv = (const float*)&v[q];
#pragma unroll
    for (int e = 0; e < 4; ++e) {
      unsigned u = __float_as_uint(pv[e]);
      key[q * 4 + e] = (u & 0x80000000u) ? ~u : (u | 0x80000000u);
    }
  }
  // max t such that count(key >= t) >= ADJ_KK  == key of 204th largest
  unsigned tk = 0u;
#pragma unroll 1
  for (int bit = 31; bit >= 0; --bit) {
    unsigned cand = tk | (1u << bit);
    int c = 0;
#pragma unroll
    for (int e = 0; e < 16; ++e) c += (key[e] >= cand) ? 1 : 0;
#pragma unroll
    for (int off = 32; off > 0; off >>= 1) c += __shfl_xor(c, off);
    if (c >= ADJ_KK) tk = cand;
  }
  // threshold (exact: key compare == float compare vs recovered thr)
  float m[16];
  float s = 0.0f;
#pragma unroll
  for (int q = 0; q < 4; ++q) {
    const float* pv = (const float*)&v[q];
#pragma unroll
    for (int e = 0; e < 4; ++e) {
      float mv = (key[q * 4 + e] >= tk) ? pv[e] : 0.0f;
      m[q * 4 + e] = mv;
      s += mv;
    }
  }
#pragma unroll
  for (int off = 32; off > 0; off >>= 1) s += __shfl_xor(s, off);
  float invF = 1.0f / (s + 1.0f + EPSF);
  float vi = im[i];
  float invP = invSumP[(size_t)b * KN + i];
#pragma unroll
  for (int q = 0; q < 4; ++q) {
    float4 iv = ((const float4*)im)[lane + 64 * q];
    const float* ip = (const float*)&iv;
    float4 r;
    float* rp = (float*)&r;
    int colb = 4 * lane + 256 * q;
#pragma unroll
    for (int e = 0; e < 4; ++e) {
      float diag = (colb + e == i) ? 1.0f : 0.0f;
      float d = vi - ip[e];
      rp[e] = (m[q * 4 + e] + diag) * invF + (__expf(-d * d * 0.125f) + diag) * invP;
    }
    ((float4*)row)[lane + 64 * q] = r;
  }
}

// ---------------- per-node linear: out[b,o,k] = sum_c f[b,c,k] W[c,o] ----
template <int C, int M, bool MASK>
__global__ void linear_kernel(const float* __restrict__ f, const float* __restrict__ W,
                              float* __restrict__ outp, const float* __restrict__ mTK) {
  int o0 = blockIdx.x * 16;
  int b = blockIdx.y;
  __shared__ float Ws[C][16];
  for (int l = threadIdx.x; l < C * 16; l += 256) {
    int c = l >> 4, o = l & 15;
    Ws[c][o] = W[(size_t)c * M + o0 + o];
  }
  __syncthreads();
  int k0 = threadIdx.x * 4;
  const float* fb = f + (size_t)b * C * KN;
  float acc[16][4] = {};
  for (int c = 0; c < C; ++c) {
    float4 xv = *(const float4*)(fb + (size_t)c * KN + k0);
#pragma unroll
    for (int o = 0; o < 16; ++o) {
      float w = Ws[c][o];
      acc[o][0] += xv.x * w;
      acc[o][1] += xv.y * w;
      acc[o][2] += xv.z * w;
      acc[o][3] += xv.w * w;
    }
  }
  float ms[4] = {1.0f, 1.0f, 1.0f, 1.0f};
  if (MASK) {
#pragma unroll
    for (int jj = 0; jj < 4; ++jj) ms[jj] = mTK[(size_t)b * KN + k0 + jj] * INV_DS;
  }
#pragma unroll
  for (int o = 0; o < 16; ++o) {
    float4 r = make_float4(acc[o][0] * ms[0], acc[o][1] * ms[1], acc[o][2] * ms[2],
                           acc[o][3] * ms[3]);
    *(float4*)(outp + ((size_t)b * M + o0 + o) * KN + k0) = r;
  }
}

// ---------------- s = relu(h @ A) ----------------------------------------
template <int M>
__global__ void sgemm_kernel(const float* __restrict__ h, const float* __restrict__ A,
                             float* __restrict__ outp, int bstart) {
  int brel = blockIdx.z;
  int b = bstart + brel;
  int j0 = blockIdx.x * 64;
  int m0 = blockIdx.y * 64;
  const float* hb = h + ((size_t)b * M + m0) * KN;
  const float* Ab = A + (size_t)brel * KN * KN;
  __shared__ float Hs[16][65];
  __shared__ float As[16][65];
  float acc[4][4] = {};
  int tx = threadIdx.x & 15, ty = threadIdx.x >> 4;
  for (int k0 = 0; k0 < KN; k0 += 16) {
    for (int l = threadIdx.x; l < 1024; l += 256) {
      int mm = l >> 4, kk = l & 15;
      Hs[kk][mm] = hb[(size_t)mm * KN + k0 + kk];
    }
    for (int l = threadIdx.x; l < 1024; l += 256) {
      int kk = l >> 6, jj = l & 63;
      As[kk][jj] = Ab[(size_t)(k0 + kk) * KN + j0 + jj];
    }
    __syncthreads();
#pragma unroll
    for (int kk = 0; kk < 16; ++kk) {
      float a[4], bb[4];
#pragma unroll
      for (int mi = 0; mi < 4; ++mi) a[mi] = Hs[kk][ty * 4 + mi];
#pragma unroll
      for (int nj = 0; nj < 4; ++nj) bb[nj] = As[kk][tx * 4 + nj];
#pragma unroll
      for (int mi = 0; mi < 4; ++mi)
#pragma unroll
        for (int nj = 0; nj < 4; ++nj) acc[mi][nj] += a[mi] * bb[nj];
    }
    __syncthreads();
  }
#pragma unroll
  for (int mi = 0; mi < 4; ++mi) {
    float4 r = make_float4(fmaxf(acc[mi][0], 0.0f), fmaxf(acc[mi][1], 0.0f),
                           fmaxf(acc[mi][2], 0.0f), fmaxf(acc[mi][3], 0.0f));
    *(float4*)(outp + ((size_t)b * M + m0 + ty * 4 + mi) * KN + j0 + tx * 4) = r;
  }
}

// ---------------- reductions ---------------------------------------------
__global__ void bag12_kernel(const float* __restrict__ emb1, const float* __restrict__ mTK,
                             const float* __restrict__ mTD, const float* __restrict__ imp,
                             float* __restrict__ bagk, float* __restrict__ bagd) {
  int c = blockIdx.x, b = blockIdx.y;
  int t = threadIdx.x;
  const float* e = emb1 + ((size_t)b * CMID + c) * KN;
  const float* ir = imp + (size_t)b * KN;
  const float* m1 = mTK + (size_t)b * KN;
  const float* m2 = mTD + (size_t)b * KN;
  float s1 = 0.0f, sd = 0.0f;
  for (int k = t; k < KN; k += 256) {
    float ev = e[k] * ir[k];
    s1 += ev * m1[k];
    sd += ev * m2[k];
  }
  __shared__ float r1[256], r2[256];
  r1[t] = s1;
  r2[t] = sd;
  __syncthreads();
  for (int st = 128; st > 0; st >>= 1) {
    if (t < st) {
      r1[t] += r1[t + st];
      r2[t] += r2[t + st];
    }
    __syncthreads();
  }
  if (t == 0) {
    bagk[(size_t)b * CMID + c] = r1[0] * INV_DS;
    bagd[(size_t)b * CMID + c] = r2[0] * INV_DS;
  }
}

__global__ void bag2_kernel(const float* __restrict__ s2, const float* __restrict__ mTK,
                            const float* __restrict__ imp, float* __restrict__ bag) {
  int o = blockIdx.x, b = blockIdx.y;
  int t = threadIdx.x;
  const float* sr = s2 + ((size_t)b * COUT + o) * KN;
  const float* ir = imp + (size_t)b * KN;
  const float* mr = mTK + (size_t)b * KN;
  float s = 0.0f;
  for (int k = t; k < KN; k += 256) s += sr[k] * mr[k] * ir[k];
  __shared__ float red[256];
  red[t] = s;
  __syncthreads();
  for (int st = 128; st > 0; st >>= 1) {
    if (t < st) red[t] += red[t + st];
    __syncthreads();
  }
  if (t == 0) bag[(size_t)b * COUT + o] = red[0];
}

__global__ void pooled_kernel(const float* __restrict__ x, const float* __restrict__ imp,
                              float* __restrict__ pooled) {
  int c = blockIdx.x, b = blockIdx.y;
  int t = threadIdx.x;
  const float* xr = x + ((size_t)b * CIN + c) * KN;
  const float* ir = imp + (size_t)b * KN;
  float s = 0.0f;
  for (int k = t; k < KN; k += 256) s += xr[k] * ir[k];
  __shared__ float red[256];
  red[t] = s;
  __syncthreads();
  for (int st = 128; st > 0; st >>= 1) {
    if (t < st) red[t] += red[t + st];
    __syncthreads();
  }
  if (t == 0) pooled[(size_t)b * CIN + c] = red[0];
}

__global__ void final_kernel(const float* __restrict__ pooled, const float* __restrict__ bag,
                             const float* __restrict__ id_w, const float* __restrict__ id_b,
                             const float* __restrict__ fc_w, float* __restrict__ out) {
  int b = blockIdx.x;
  int o = threadIdx.x;
  __shared__ float v[COUT];
  float s = id_b[o];
  const float* pr = pooled + (size_t)b * CIN;
  for (int c = 0; c < CIN; ++c) s += pr[c] * id_w[(size_t)c * COUT + o];
  v[o] = bag[(size_t)b * COUT + o] + fmaxf(s, 0.0f);
  __syncthreads();
  if (o < NCLS) {
    float acc = 0.0f;
    for (int oo = 0; oo < COUT; ++oo) acc += v[oo] * fc_w[(size_t)oo * NCLS + o];
    out[(size_t)b * NCLS + o] = acc;
  }
}

// ---------------- launch --------------------------------------------------
extern "C" void kernel_launch(void* const* d_in, const int* in_sizes, int n_in,
                              void* d_out, int out_size, void* d_ws, size_t ws_size,
                              hipStream_t stream) {
  const float* x = (const float*)d_in[0];
  const float* imp = (const float*)d_in[1];
  const float* rnd = (const float*)d_in[2];
  const float* W1 = (const float*)d_in[3];
  const float* W2 = (const float*)d_in[4];
  const float* fc_w = (const float*)d_in[5];
  const float* id_w = (const float*)d_in[6];
  const float* id_b = (const float*)d_in[7];
  float* out = (float*)d_out;
  float* emb1 = out + BN_ * NCLS;
  float* bagk = emb1 + (size_t)BN_ * CMID * KN;
  float* bagd = bagk + (size_t)BN_ * CMID;

  float* w = (float*)d_ws;
  size_t off = 0;
  auto take = [&](size_t n) {
    float* p = w + off;
    off += n;
    return p;
  };
  float* invSumP = take((size_t)BN_ * KN);
  float* invNX = take((size_t)BN_ * KN);
  float* invNE = take((size_t)BN_ * KN);
  float* mTK = take((size_t)BN_ * KN);
  float* mTD = take((size_t)BN_ * KN);
  float* h = take((size_t)BN_ * CMID * KN);
  float* h2 = take((size_t)BN_ * COUT * KN);
  float* s2 = take((size_t)BN_ * COUT * KN);
  float* bag = take((size_t)BN_ * COUT);
  float* pooled = take((size_t)BN_ * CIN);
  __hip_bfloat16* xnT = (__hip_bfloat16*)take((size_t)BN_ * CIN * KN / 2);
  __hip_bfloat16* enT = (__hip_bfloat16*)take((size_t)BN_ * CMID * KN / 2);
  long long avail = (long long)(ws_size / 4) - (long long)off;
  int nb = 1;
  const int cands[6] = {32, 16, 8, 4, 2, 1};
  for (int ci = 0; ci < 6; ++ci) {
    if ((long long)cands[ci] * KN * KN <= avail) {
      nb = cands[ci];
      break;
    }
  }
  float* simA = w + off;

  masks_kernel<<<BN_, 1024, 0, stream>>>(imp, rnd, mTK, mTD);
  psum_kernel<<<dim3(KN / 256, BN_), 256, 0, stream>>>(imp, invSumP);
  colnorm_kernel<CIN><<<(BN_ * KN) / 256, 256, 0, stream>>>(x, invNX);
  xpose_kernel<CIN><<<dim3(KN / 64, CIN / 64, BN_), 256, 0, stream>>>(x, invNX, xnT);
  linear_kernel<CIN, CMID, false><<<dim3(CMID / 16, BN_), 256, 0, stream>>>(x, W1, h, nullptr);

  for (int bs = 0; bs < BN_; bs += nb) {
    simf_kernel<CIN><<<dim3(KN / 128, KN / 128, nb), 256, 0, stream>>>(xnT, simA, bs);
    thrfin_kernel<<<dim3(KN / 4, nb), 256, 0, stream>>>(simA, imp, invSumP, bs);
    sgemm_kernel<CMID><<<dim3(16, CMID / 64, nb), 256, 0, stream>>>(h, simA, emb1, bs);
  }

  colnorm_kernel<CMID><<<(BN_ * KN) / 256, 256, 0, stream>>>(emb1, invNE);
  xpose_kernel<CMID><<<dim3(KN / 64, CMID / 64, BN_), 256, 0, stream>>>(emb1, invNE, enT);
  linear_kernel<CMID, COUT, true><<<dim3(COUT / 16, BN_), 256, 0, stream>>>(emb1, W2, h2, mTK);

  for (int bs = 0; bs < BN_; bs += nb) {
    simf_kernel<CMID><<<dim3(KN / 128, KN / 128, nb), 256, 0, stream>>>(enT, simA, bs);
    thrfin_kernel<<<dim3(KN / 4, nb), 256, 0, stream>>>(simA, imp, invSumP, bs);
    sgemm_kernel<COUT><<<dim3(16, COUT / 64, nb), 256, 0, stream>>>(h2, simA, s2, bs);
  }

  bag12_kernel<<<dim3(CMID, BN_), 256, 0, stream>>>(emb1, mTK, mTD, imp, bagk, bagd);
  bag2_kernel<<<dim3(COUT, BN_), 256, 0, stream>>>(s2, mTK, imp, bag);
  pooled_kernel<<<dim3(CIN, BN_), 256, 0, stream>>>(x, imp, pooled);
  final_kernel<<<BN_, 64, 0, stream>>>(pooled, bag, id_w, id_b, fc_w, out);
}

// Round 4
// 860.907 us; speedup vs baseline: 3.2438x; 1.3612x over previous
//
#include <hip/hip_runtime.h>
#include <hip/hip_bf16.h>
#include <math.h>

#define BN_ 32
#define CIN 512
#define KN 1024
#define CMID 128
#define COUT 64
#define NCLS 5
#define NUM_TOP 205
#define NUM_KEPT 409
#define NUM_DROP 410
#define ADJ_KK 204
#define EPSF 1e-8f
#define INV_DS (1.0f / 0.599609375f)

typedef __bf16 bf16x8 __attribute__((ext_vector_type(8)));
typedef float f32x4 __attribute__((ext_vector_type(4)));

__device__ inline ushort f2bf(float x) {
  union { __hip_bfloat16 b; ushort u; } c;
  c.b = __float2bfloat16(x);
  return c.u;
}

// ---------------- masks: exact stable top-k semantics via rank counting ----
__global__ __launch_bounds__(1024) void masks_kernel(const float* __restrict__ imp,
                                                     const float* __restrict__ rnd,
                                                     float* __restrict__ mTK,
                                                     float* __restrict__ mTD) {
  int b = blockIdx.x;
  int i = threadIdx.x;
  __shared__ float im[KN];
  __shared__ float rm[KN];
  __shared__ float r1[KN];
  im[i] = imp[(size_t)b * KN + i];
  rm[i] = rnd[(size_t)b * KN + i];
  __syncthreads();
  float vi = im[i];
  int rank = 0;
  for (int j = 0; j < KN; ++j) {
    float vj = im[j];
    rank += (vj > vi || (vj == vi && j < i)) ? 1 : 0;
  }
  int top = rank < NUM_TOP;
  r1[i] = top ? -10.0f : rm[i];
  __syncthreads();
  float v1 = r1[i];
  int rank1 = 0;
  for (int j = 0; j < KN; ++j) {
    float vj = r1[j];
    rank1 += (vj > v1 || (vj == v1 && j < i)) ? 1 : 0;
  }
  int kept = rank1 < NUM_KEPT;
  __syncthreads();
  r1[i] = top ? 10.0f : rm[i];
  __syncthreads();
  float v2 = r1[i];
  int rank2 = 0;
  for (int j = 0; j < KN; ++j) {
    float vj = r1[j];
    rank2 += (vj < v2 || (vj == v2 && j < i)) ? 1 : 0;
  }
  int drop = rank2 < NUM_DROP;
  mTK[(size_t)b * KN + i] = (top || kept) ? 1.0f : 0.0f;
  mTD[(size_t)b * KN + i] = (top || drop) ? 1.0f : 0.0f;
}

// ---------------- adjP row-sum reciprocals -------------------------------
__global__ void psum_kernel(const float* __restrict__ imp, float* __restrict__ invSumP) {
  int b = blockIdx.y;
  int i = blockIdx.x * 256 + threadIdx.x;
  __shared__ float im[KN];
  for (int j = threadIdx.x; j < KN; j += 256) im[j] = imp[(size_t)b * KN + j];
  __syncthreads();
  float vi = im[i];
  float s = 0.0f;
  for (int j = 0; j < KN; ++j) {
    float d = vi - im[j];
    s += __expf(-d * d * 0.125f);
  }
  invSumP[(size_t)b * KN + i] = 1.0f / (s + 1.0f + EPSF);
}

// ---------------- per-column L2 norm reciprocals -------------------------
template <int C>
__global__ void colnorm_kernel(const float* __restrict__ f, float* __restrict__ inv) {
  int idx = blockIdx.x * 256 + threadIdx.x;
  int b = idx >> 10;
  int k = idx & (KN - 1);
  const float* fb = f + (size_t)b * C * KN + k;
  float ss = 0.0f;
  for (int c = 0; c < C; ++c) {
    float v = fb[(size_t)c * KN];
    ss += v * v;
  }
  inv[idx] = 1.0f / (sqrtf(ss) + EPSF);
}

// ------- transpose + normalize + bf16: oT[b][k][c] = f[b][c][k]*inv[b][k] --
template <int C>
__global__ void xpose_kernel(const float* __restrict__ f, const float* __restrict__ inv,
                             __hip_bfloat16* __restrict__ oT) {
  int b = blockIdx.z;
  int k0 = blockIdx.x * 64;
  int c0 = blockIdx.y * 64;
  __shared__ float t[64][65];
  const float* fb = f + (size_t)b * C * KN;
  int tx = threadIdx.x & 63;
  int ty = threadIdx.x >> 6;
  for (int r = 0; r < 64; r += 4) t[r + ty][tx] = fb[(size_t)(c0 + r + ty) * KN + k0 + tx];
  __syncthreads();
  __hip_bfloat16* ob = oT + (size_t)b * KN * C;
  for (int r = 0; r < 64; r += 4) {
    int k = r + ty;
    float s = inv[(size_t)b * KN + k0 + k];
    ob[(size_t)(k0 + k) * C + c0 + tx] = __float2bfloat16(t[tx][k] * s);
  }
}

// ---------------- MFMA sim: sim = XnT * XnT^T (Gram, symmetric) ----------
template <int C>
__global__ __launch_bounds__(256) void simf_kernel(const __hip_bfloat16* __restrict__ xT,
                                                   float* __restrict__ sim, int bstart) {
  int brel = blockIdx.z;
  int b = bstart + brel;
  int lane = threadIdx.x & 63;
  int wid = threadIdx.x >> 6;
  int i0 = blockIdx.y * 128 + (wid >> 1) * 64;
  int j0 = blockIdx.x * 128 + (wid & 1) * 64;
  const __hip_bfloat16* X = xT + (size_t)b * KN * C;
  int lrow = lane & 15;
  int koff = (lane >> 4) * 8;
  f32x4 acc[4][4] = {};
#pragma unroll 4
  for (int c0 = 0; c0 < C; c0 += 32) {
    bf16x8 a[4], bb[4];
#pragma unroll
    for (int m = 0; m < 4; ++m)
      a[m] = *reinterpret_cast<const bf16x8*>(X + (size_t)(i0 + m * 16 + lrow) * C + c0 + koff);
#pragma unroll
    for (int n = 0; n < 4; ++n)
      bb[n] = *reinterpret_cast<const bf16x8*>(X + (size_t)(j0 + n * 16 + lrow) * C + c0 + koff);
#pragma unroll
    for (int m = 0; m < 4; ++m)
#pragma unroll
      for (int n = 0; n < 4; ++n)
        acc[m][n] = __builtin_amdgcn_mfma_f32_16x16x32_bf16(a[m], bb[n], acc[m][n], 0, 0, 0);
  }
  int orow = (lane >> 4) * 4;
  int ocol = lane & 15;
  float* simb = sim + (size_t)brel * KN * KN;
#pragma unroll
  for (int m = 0; m < 4; ++m)
#pragma unroll
    for (int n = 0; n < 4; ++n) {
#pragma unroll
      for (int r = 0; r < 4; ++r)
        simb[(size_t)(i0 + m * 16 + orow + r) * KN + j0 + n * 16 + ocol] = acc[m][n][r];
    }
}

// ------- fused per-wave threshold select + finalize ----------------------
// One row per wave; 4 rows per block. Exact 204th-largest via 32-step
// bit-building bisection on monotone u32 keys held in registers, then
// A = norm(where(sim>=thr,sim,0)+I) + norm(adjP) written IN PLACE as bf16
// (row stride stays 2048 ushorts = the f32 row slot).
__global__ __launch_bounds__(256) void thrfin_kernel(float* __restrict__ A,
                                                     const float* __restrict__ imp,
                                                     const float* __restrict__ invSumP,
                                                     int bstart) {
  int brel = blockIdx.y;
  int b = bstart + brel;
  int wid = threadIdx.x >> 6;
  int lane = threadIdx.x & 63;
  int i = blockIdx.x * 4 + wid;
  float* row = A + ((size_t)brel * KN + i) * KN;
  __shared__ float im[KN];
  ((float4*)im)[threadIdx.x] = ((const float4*)(imp + (size_t)b * KN))[threadIdx.x];
  __syncthreads();

  float4 v[4];
  unsigned key[16];
#pragma unroll
  for (int q = 0; q < 4; ++q) v[q] = ((const float4*)row)[lane + 64 * q];
#pragma unroll
  for (int q = 0; q < 4; ++q) {
    const float* pv = (const float*)&v[q];
#pragma unroll
    for (int e = 0; e < 4; ++e) {
      unsigned u = __float_as_uint(pv[e]);
      key[q * 4 + e] = (u & 0x80000000u) ? ~u : (u | 0x80000000u);
    }
  }
  unsigned tk = 0u;
#pragma unroll 1
  for (int bit = 31; bit >= 0; --bit) {
    unsigned cand = tk | (1u << bit);
    int c = 0;
#pragma unroll
    for (int e = 0; e < 16; ++e) c += (key[e] >= cand) ? 1 : 0;
#pragma unroll
    for (int off = 32; off > 0; off >>= 1) c += __shfl_xor(c, off);
    if (c >= ADJ_KK) tk = cand;
  }
  float m[16];
  float s = 0.0f;
#pragma unroll
  for (int q = 0; q < 4; ++q) {
    const float* pv = (const float*)&v[q];
#pragma unroll
    for (int e = 0; e < 4; ++e) {
      float mv = (key[q * 4 + e] >= tk) ? pv[e] : 0.0f;
      m[q * 4 + e] = mv;
      s += mv;
    }
  }
#pragma unroll
  for (int off = 32; off > 0; off >>= 1) s += __shfl_xor(s, off);
  float invF = 1.0f / (s + 1.0f + EPSF);
  float vi = im[i];
  float invP = invSumP[(size_t)b * KN + i];
  ushort* rowb = (ushort*)row;
#pragma unroll
  for (int q = 0; q < 4; ++q) {
    float4 iv = ((const float4*)im)[lane + 64 * q];
    const float* ip = (const float*)&iv;
    ushort4 r;
    ushort* rp = (ushort*)&r;
    int colb = 4 * lane + 256 * q;
#pragma unroll
    for (int e = 0; e < 4; ++e) {
      float diag = (colb + e == i) ? 1.0f : 0.0f;
      float d = vi - ip[e];
      rp[e] = f2bf((m[q * 4 + e] + diag) * invF + (__expf(-d * d * 0.125f) + diag) * invP);
    }
    ((ushort4*)rowb)[lane + 64 * q] = r;
  }
}

// ------- bf16 transpose: At[b][j][k] = A[b][k][j] (A row stride 2048) ----
__global__ void at_kernel(const float* __restrict__ Asim, ushort* __restrict__ At) {
  int brel = blockIdx.z;
  int k0 = blockIdx.x * 64;
  int j0 = blockIdx.y * 64;
  __shared__ ushort t[64][65];
  const ushort* Ab = (const ushort*)(Asim + (size_t)brel * KN * KN);
  int tx = threadIdx.x & 63;
  int ty = threadIdx.x >> 6;
  for (int r = 0; r < 64; r += 4) t[r + ty][tx] = Ab[(size_t)(k0 + r + ty) * 2048 + j0 + tx];
  __syncthreads();
  ushort* ob = At + (size_t)brel * KN * KN;
  for (int r = 0; r < 64; r += 4) ob[(size_t)(j0 + r + ty) * KN + k0 + tx] = t[tx][r + ty];
}

// ---------------- per-node linear: h[b,o,k] = sum_c f[b,c,k] W[c,o] (bf16 out)
template <int C, int M, bool MASK>
__global__ void linear_kernel(const float* __restrict__ f, const float* __restrict__ W,
                              ushort* __restrict__ outp, const float* __restrict__ mTK) {
  int o0 = blockIdx.x * 16;
  int b = blockIdx.y;
  __shared__ float Ws[C][16];
  for (int l = threadIdx.x; l < C * 16; l += 256) {
    int c = l >> 4, o = l & 15;
    Ws[c][o] = W[(size_t)c * M + o0 + o];
  }
  __syncthreads();
  int k0 = threadIdx.x * 4;
  const float* fb = f + (size_t)b * C * KN;
  float acc[16][4] = {};
  for (int c = 0; c < C; ++c) {
    float4 xv = *(const float4*)(fb + (size_t)c * KN + k0);
#pragma unroll
    for (int o = 0; o < 16; ++o) {
      float w = Ws[c][o];
      acc[o][0] += xv.x * w;
      acc[o][1] += xv.y * w;
      acc[o][2] += xv.z * w;
      acc[o][3] += xv.w * w;
    }
  }
  float ms[4] = {1.0f, 1.0f, 1.0f, 1.0f};
  if (MASK) {
#pragma unroll
    for (int jj = 0; jj < 4; ++jj) ms[jj] = mTK[(size_t)b * KN + k0 + jj] * INV_DS;
  }
#pragma unroll
  for (int o = 0; o < 16; ++o) {
    ushort4 r;
    r.x = f2bf(acc[o][0] * ms[0]);
    r.y = f2bf(acc[o][1] * ms[1]);
    r.z = f2bf(acc[o][2] * ms[2]);
    r.w = f2bf(acc[o][3] * ms[3]);
    *(ushort4*)(outp + ((size_t)b * M + o0 + o) * KN + k0) = r;
  }
}

// ---------------- MFMA s = relu(h @ A) via At ----------------------------
template <int M>
__global__ __launch_bounds__(256) void sgemmf_kernel(const ushort* __restrict__ hB,
                                                     const ushort* __restrict__ At,
                                                     float* __restrict__ outp, int bstart) {
  constexpr int MF = (M == 128) ? 4 : 2;
  int brel = blockIdx.z;
  int b = bstart + brel;
  int lane = threadIdx.x & 63;
  int wid = threadIdx.x >> 6;
  int i0 = (wid >> 1) * (16 * MF);
  int j0 = blockIdx.x * 128 + (wid & 1) * 64;
  const ushort* hb = hB + (size_t)b * M * KN;
  const ushort* Ab = At + (size_t)brel * KN * KN;
  int lrow = lane & 15;
  int koff = (lane >> 4) * 8;
  f32x4 acc[MF][4] = {};
#pragma unroll 2
  for (int k0 = 0; k0 < KN; k0 += 32) {
    bf16x8 a[MF], bb[4];
#pragma unroll
    for (int m = 0; m < MF; ++m)
      a[m] = *reinterpret_cast<const bf16x8*>(hb + (size_t)(i0 + m * 16 + lrow) * KN + k0 + koff);
#pragma unroll
    for (int n = 0; n < 4; ++n)
      bb[n] = *reinterpret_cast<const bf16x8*>(Ab + (size_t)(j0 + n * 16 + lrow) * KN + k0 + koff);
#pragma unroll
    for (int m = 0; m < MF; ++m)
#pragma unroll
      for (int n = 0; n < 4; ++n)
        acc[m][n] = __builtin_amdgcn_mfma_f32_16x16x32_bf16(a[m], bb[n], acc[m][n], 0, 0, 0);
  }
  int orow = (lane >> 4) * 4;
  int ocol = lane & 15;
  float* ob = outp + (size_t)b * M * KN;
#pragma unroll
  for (int m = 0; m < MF; ++m)
#pragma unroll
    for (int n = 0; n < 4; ++n) {
#pragma unroll
      for (int r = 0; r < 4; ++r)
        ob[(size_t)(i0 + m * 16 + orow + r) * KN + j0 + n * 16 + ocol] =
            fmaxf(acc[m][n][r], 0.0f);
    }
}

// ---------------- reductions ---------------------------------------------
__global__ void bag12_kernel(const float* __restrict__ emb1, const float* __restrict__ mTK,
                             const float* __restrict__ mTD, const float* __restrict__ imp,
                             float* __restrict__ bagk, float* __restrict__ bagd) {
  int c = blockIdx.x, b = blockIdx.y;
  int t = threadIdx.x;
  const float* e = emb1 + ((size_t)b * CMID + c) * KN;
  const float* ir = imp + (size_t)b * KN;
  const float* m1 = mTK + (size_t)b * KN;
  const float* m2 = mTD + (size_t)b * KN;
  float s1 = 0.0f, sd = 0.0f;
  for (int k = t; k < KN; k += 256) {
    float ev = e[k] * ir[k];
    s1 += ev * m1[k];
    sd += ev * m2[k];
  }
  __shared__ float r1[256], r2[256];
  r1[t] = s1;
  r2[t] = sd;
  __syncthreads();
  for (int st = 128; st > 0; st >>= 1) {
    if (t < st) {
      r1[t] += r1[t + st];
      r2[t] += r2[t + st];
    }
    __syncthreads();
  }
  if (t == 0) {
    bagk[(size_t)b * CMID + c] = r1[0] * INV_DS;
    bagd[(size_t)b * CMID + c] = r2[0] * INV_DS;
  }
}

__global__ void bag2_kernel(const float* __restrict__ s2, const float* __restrict__ mTK,
                            const float* __restrict__ imp, float* __restrict__ bag) {
  int o = blockIdx.x, b = blockIdx.y;
  int t = threadIdx.x;
  const float* sr = s2 + ((size_t)b * COUT + o) * KN;
  const float* ir = imp + (size_t)b * KN;
  const float* mr = mTK + (size_t)b * KN;
  float s = 0.0f;
  for (int k = t; k < KN; k += 256) s += sr[k] * mr[k] * ir[k];
  __shared__ float red[256];
  red[t] = s;
  __syncthreads();
  for (int st = 128; st > 0; st >>= 1) {
    if (t < st) red[t] += red[t + st];
    __syncthreads();
  }
  if (t == 0) bag[(size_t)b * COUT + o] = red[0];
}

__global__ void pooled_kernel(const float* __restrict__ x, const float* __restrict__ imp,
                              float* __restrict__ pooled) {
  int c = blockIdx.x, b = blockIdx.y;
  int t = threadIdx.x;
  const float* xr = x + ((size_t)b * CIN + c) * KN;
  const float* ir = imp + (size_t)b * KN;
  float s = 0.0f;
  for (int k = t; k < KN; k += 256) s += xr[k] * ir[k];
  __shared__ float red[256];
  red[t] = s;
  __syncthreads();
  for (int st = 128; st > 0; st >>= 1) {
    if (t < st) red[t] += red[t + st];
    __syncthreads();
  }
  if (t == 0) pooled[(size_t)b * CIN + c] = red[0];
}

__global__ void final_kernel(const float* __restrict__ pooled, const float* __restrict__ bag,
                             const float* __restrict__ id_w, const float* __restrict__ id_b,
                             const float* __restrict__ fc_w, float* __restrict__ out) {
  int b = blockIdx.x;
  int o = threadIdx.x;
  __shared__ float v[COUT];
  float s = id_b[o];
  const float* pr = pooled + (size_t)b * CIN;
  for (int c = 0; c < CIN; ++c) s += pr[c] * id_w[(size_t)c * COUT + o];
  v[o] = bag[(size_t)b * COUT + o] + fmaxf(s, 0.0f);
  __syncthreads();
  if (o < NCLS) {
    float acc = 0.0f;
    for (int oo = 0; oo < COUT; ++oo) acc += v[oo] * fc_w[(size_t)oo * NCLS + o];
    out[(size_t)b * NCLS + o] = acc;
  }
}

// ---------------- launch --------------------------------------------------
extern "C" void kernel_launch(void* const* d_in, const int* in_sizes, int n_in,
                              void* d_out, int out_size, void* d_ws, size_t ws_size,
                              hipStream_t stream) {
  const float* x = (const float*)d_in[0];
  const float* imp = (const float*)d_in[1];
  const float* rnd = (const float*)d_in[2];
  const float* W1 = (const float*)d_in[3];
  const float* W2 = (const float*)d_in[4];
  const float* fc_w = (const float*)d_in[5];
  const float* id_w = (const float*)d_in[6];
  const float* id_b = (const float*)d_in[7];
  float* out = (float*)d_out;
  float* emb1 = out + BN_ * NCLS;
  float* bagk = emb1 + (size_t)BN_ * CMID * KN;
  float* bagd = bagk + (size_t)BN_ * CMID;

  float* w = (float*)d_ws;
  size_t off = 0;
  auto take = [&](size_t n) {
    float* p = w + off;
    off += n;
    return p;
  };
  float* invSumP = take((size_t)BN_ * KN);
  float* invNX = take((size_t)BN_ * KN);
  float* invNE = take((size_t)BN_ * KN);
  float* mTK = take((size_t)BN_ * KN);
  float* mTD = take((size_t)BN_ * KN);
  ushort* h = (ushort*)take((size_t)BN_ * CMID * KN / 2);
  ushort* h2 = (ushort*)take((size_t)BN_ * COUT * KN / 2);
  float* s2 = take((size_t)BN_ * COUT * KN);
  float* bag = take((size_t)BN_ * COUT);
  float* pooled = take((size_t)BN_ * CIN);
  __hip_bfloat16* xnT = (__hip_bfloat16*)take((size_t)BN_ * CIN * KN / 2);
  __hip_bfloat16* enT = (__hip_bfloat16*)take((size_t)BN_ * CMID * KN / 2);
  long long avail = (long long)(ws_size / 4) - (long long)off;
  int nb = 1;
  const int cands[6] = {32, 16, 8, 4, 2, 1};
  for (int ci = 0; ci < 6; ++ci) {
    if ((long long)cands[ci] * KN * KN * 3 / 2 <= avail) {
      nb = cands[ci];
      break;
    }
  }
  float* simA = take((size_t)nb * KN * KN);
  ushort* At = (ushort*)take((size_t)nb * KN * KN / 2);

  masks_kernel<<<BN_, 1024, 0, stream>>>(imp, rnd, mTK, mTD);
  psum_kernel<<<dim3(KN / 256, BN_), 256, 0, stream>>>(imp, invSumP);
  colnorm_kernel<CIN><<<(BN_ * KN) / 256, 256, 0, stream>>>(x, invNX);
  xpose_kernel<CIN><<<dim3(KN / 64, CIN / 64, BN_), 256, 0, stream>>>(x, invNX, xnT);
  linear_kernel<CIN, CMID, false><<<dim3(CMID / 16, BN_), 256, 0, stream>>>(x, W1, h, nullptr);

  for (int bs = 0; bs < BN_; bs += nb) {
    simf_kernel<CIN><<<dim3(KN / 128, KN / 128, nb), 256, 0, stream>>>(xnT, simA, bs);
    thrfin_kernel<<<dim3(KN / 4, nb), 256, 0, stream>>>(simA, imp, invSumP, bs);
    at_kernel<<<dim3(KN / 64, KN / 64, nb), 256, 0, stream>>>(simA, At);
    sgemmf_kernel<CMID><<<dim3(KN / 128, 1, nb), 256, 0, stream>>>(h, At, emb1, bs);
  }

  colnorm_kernel<CMID><<<(BN_ * KN) / 256, 256, 0, stream>>>(emb1, invNE);
  xpose_kernel<CMID><<<dim3(KN / 64, CMID / 64, BN_), 256, 0, stream>>>(emb1, invNE, enT);
  linear_kernel<CMID, COUT, true><<<dim3(COUT / 16, BN_), 256, 0, stream>>>(emb1, W2, h2, mTK);

  for (int bs = 0; bs < BN_; bs += nb) {
    simf_kernel<CMID><<<dim3(KN / 128, KN / 128, nb), 256, 0, stream>>>(enT, simA, bs);
    thrfin_kernel<<<dim3(KN / 4, nb), 256, 0, stream>>>(simA, imp, invSumP, bs);
    at_kernel<<<dim3(KN / 64, KN / 64, nb), 256, 0, stream>>>(simA, At);
    sgemmf_kernel<COUT><<<dim3(KN / 128, 1, nb), 256, 0, stream>>>(h2, At, s2, bs);
  }

  bag12_kernel<<<dim3(CMID, BN_), 256, 0, stream>>>(emb1, mTK, mTD, imp, bagk, bagd);
  bag2_kernel<<<dim3(COUT, BN_), 256, 0, stream>>>(s2, mTK, imp, bag);
  pooled_kernel<<<dim3(CIN, BN_), 256, 0, stream>>>(x, imp, pooled);
  final_kernel<<<BN_, 64, 0, stream>>>(pooled, bag, id_w, id_b, fc_w, out);
}